// Round 6
// baseline (138.568 us; speedup 1.0000x reference)
//
#include <hip/hip_runtime.h>
#include <stdint.h>

// Problem constants
#define B_  1024
#define D_  512
#define K_  255
#define L_  256
#define C_  80

typedef __attribute__((ext_vector_type(8))) short bf16x8;
typedef __attribute__((ext_vector_type(4))) float f32x4;
typedef __attribute__((ext_vector_type(8))) short short8;

// async global->LDS, 16B per lane; dst must be wave-uniform base + lane*16.
#define GLD(gsrc, ldst) \
  __builtin_amdgcn_global_load_lds((const __attribute__((address_space(1))) void*)(gsrc), \
                                   (__attribute__((address_space(3))) void*)(ldst), 16, 0, 0)

__device__ __forceinline__ short cvt_bf16(float f) {
    unsigned u = __float_as_uint(f);
    u += 0x7FFFu + ((u >> 16) & 1u);
    return (short)(u >> 16);
}

// ---------------------------------------------------------------------------
// Kernel 1: convert W (20480x512) + x (1024x512) fp32->bf16, AND normalize
// ne rows -> bf16 neb (256 rows; row 255 zeroed).  Memory-bound (~66 MB),
// measured ~11 us ~= its 67 MB / 6.3 TB/s floor. Leave alone.
// ---------------------------------------------------------------------------
__global__ __launch_bounds__(256) void convert_kernel(const float* __restrict__ w,
                                                      const float* __restrict__ x,
                                                      const float* __restrict__ ne,
                                                      short* __restrict__ wb,
                                                      short* __restrict__ xb,
                                                      short* __restrict__ neb) {
    __shared__ float red[256];
    const int tid = threadIdx.x;
    if (blockIdx.x < 2048) {
        size_t i0 = (size_t)blockIdx.x * 256 + tid;
        const size_t stride = 2048u * 256u;
        for (size_t v = i0; v < 1310720u; v += stride) {
            float4 a = ((const float4*)w)[v * 2];
            float4 b = ((const float4*)w)[v * 2 + 1];
            short8 o;
            o[0] = cvt_bf16(a.x); o[1] = cvt_bf16(a.y); o[2] = cvt_bf16(a.z); o[3] = cvt_bf16(a.w);
            o[4] = cvt_bf16(b.x); o[5] = cvt_bf16(b.y); o[6] = cvt_bf16(b.z); o[7] = cvt_bf16(b.w);
            ((short8*)wb)[v] = o;
        }
        for (size_t v = i0; v < 65536u; v += stride) {
            float4 a = ((const float4*)x)[v * 2];
            float4 b = ((const float4*)x)[v * 2 + 1];
            short8 o;
            o[0] = cvt_bf16(a.x); o[1] = cvt_bf16(a.y); o[2] = cvt_bf16(a.z); o[3] = cvt_bf16(a.w);
            o[4] = cvt_bf16(b.x); o[5] = cvt_bf16(b.y); o[6] = cvt_bf16(b.z); o[7] = cvt_bf16(b.w);
            ((short8*)xb)[v] = o;
        }
    } else {
        const int row = blockIdx.x - 2048;  // 0..255
        if (row == 255) {
            ((unsigned*)(neb + 255 * 512))[tid] = 0u;  // pad row = zeros
            return;
        }
        const float2* nr = (const float2*)(ne + (size_t)row * 512);
        float2 a = nr[tid];
        red[tid] = a.x * a.x + a.y * a.y;
        __syncthreads();
        #pragma unroll
        for (int s = 128; s > 0; s >>= 1) {
            if (tid < s) red[tid] += red[tid + s];
            __syncthreads();
        }
        float inv = rsqrtf(red[0]);
        unsigned lo = (unsigned short)cvt_bf16(a.x * inv);
        unsigned hi = (unsigned short)cvt_bf16(a.y * inv);
        ((unsigned*)(neb + (size_t)row * 512))[tid] = lo | (hi << 16);
    }
}

// ---------------------------------------------------------------------------
// Kernel 2: sim GEMM: out1[b,k] = sigmoid(xb[b,:]·neb[k,:]). 64x64 tiles.
// ---------------------------------------------------------------------------
__global__ __launch_bounds__(256) void simgemm_kernel(const short* __restrict__ xb,
                                                      const short* __restrict__ neb,
                                                      float* __restrict__ out1) {
    __shared__ __align__(16) short Ald[512 * 8];
    __shared__ __align__(16) short Bld[512 * 8];
    const int tid = threadIdx.x;
    const int lane = tid & 63, wave = tid >> 6;
    const int q = lane >> 4, r = lane & 15;
    const int mt = blockIdx.x >> 2;
    const int nt = blockIdx.x & 3;

    f32x4 acc[4];
    #pragma unroll
    for (int nf = 0; nf < 4; ++nf) acc[nf] = (f32x4){0.f, 0.f, 0.f, 0.f};

    const bf16x8* Av = (const bf16x8*)Ald;
    const bf16x8* Bv = (const bf16x8*)Bld;

    for (int kb = 0; kb < 8; ++kb) {
        __syncthreads();
        #pragma unroll
        for (int j = 0; j < 2; ++j) {
            int ph = j * 256 + tid, rr = ph >> 3, g = (ph & 7) ^ (rr & 7);
            GLD(xb + ((size_t)(mt * 64 + rr) * D_ + kb * 64 + g * 8), Ald + ph * 8);
        }
        #pragma unroll
        for (int j = 0; j < 2; ++j) {
            int ph = j * 256 + tid, cc = ph >> 3, g = (ph & 7) ^ (cc & 7);
            GLD(neb + ((size_t)(nt * 64 + cc) * D_ + kb * 64 + g * 8), Bld + ph * 8);
        }
        __syncthreads();
        #pragma unroll
        for (int ks = 0; ks < 2; ++ks) {
            const int g = ks * 4 + q;
            int rl = wave * 16 + r;
            bf16x8 af = Av[rl * 8 + (g ^ (rl & 7))];
            #pragma unroll
            for (int nf = 0; nf < 4; ++nf) {
                int cl = nf * 16 + r;
                bf16x8 bfr = Bv[cl * 8 + (g ^ (cl & 7))];
                acc[nf] = __builtin_amdgcn_mfma_f32_16x16x32_bf16(af, bfr, acc[nf], 0, 0, 0);
            }
        }
    }
    #pragma unroll
    for (int nf = 0; nf < 4; ++nf) {
        int gcol = nt * 64 + nf * 16 + r;
        if (gcol < K_) {
            #pragma unroll
            for (int i = 0; i < 4; ++i) {
                int grow = mt * 64 + wave * 16 + q * 4 + i;
                out1[(size_t)grow * K_ + gcol] = 1.f / (1.f + __expf(-acc[nf][i]));
            }
        }
    }
}

// ---------------------------------------------------------------------------
// Kernel 3: leaf probabilities from out1 sigmoids. Block = batch row.
// Also zeroes out0 (runs before gemm/reduce; reduce atomicAdds into it).
// ---------------------------------------------------------------------------
__global__ __launch_bounds__(256) void leafprob_kernel(const float* __restrict__ out1,
                                                       float* __restrict__ p_ws,
                                                       float* __restrict__ out0) {
    __shared__ float ss[K_];
    const int b = blockIdx.x, t = threadIdx.x;
    if (t < K_) ss[t] = out1[(size_t)b * K_ + t];
    if (t < C_) out0[(size_t)b * C_ + t] = 0.f;   // zero-init for reduce atomics
    __syncthreads();
    float prob = 1.f;
    int node = 0;
    #pragma unroll
    for (int d = 0; d < 8; ++d) {
        int bit = (t >> (7 - d)) & 1;
        float s = ss[node];
        prob *= bit ? (1.f - s) : s;
        node = 2 * node + 1 + bit;
    }
    p_ws[(size_t)b * L_ + t] = prob;
}

// ---------------------------------------------------------------------------
// Kernel 4: main GEMM — round-5 structure with M-TILE DOUBLED to 256 rows
// via 512-thread blocks.
// Round-6 theory: corrected per-CU accounting (B per block = 320 KB, not
// 1.3 MB) shows every pipe <=21% of runtime across rounds 0/4/5 — the kernel
// is latency-bound at 2 waves/SIMD, and stage-count/byte knobs are flat
// (r0 31.5 ~= r5 32 us). The untouched first-order lever is W reuse: W is
// pulled through L2 8x (once per mt). Doubling M-tile to 256 rows halves
// that (4 mt), cuts per-CU staged bytes 896->576 KB, with the per-wave
// register shape, per-SIMD wave count (2), swizzle, and stage rhythm all
// IDENTICAL to round 5. Grid 256 blocks = exactly 1/CU, no tail.
// LDS: A 64 KB + B 2x20 KB + p 4 KB = 108 KB -> 1 block/CU at (512,1).
// Risk (deliberate experiment): no co-resident block covers the per-stage
// vmcnt(0) drain. If flat vs r5, drains are the binding constraint -> next
// round adds B double-buffer (52 KB LDS headroom) with counted vmcnt.
// Grid = mt(4) x lc(64) = 256; blockIdx%8 = lc%8 keeps the 4 m-tiles
// sharing a W slab on one XCD (L2-resident).
// ---------------------------------------------------------------------------
__global__ __launch_bounds__(512, 1) void gemm_kernel(const short* __restrict__ xb,
                                                      const short* __restrict__ wb,
                                                      const float* __restrict__ p,
                                                      const float* __restrict__ lb,
                                                      float* __restrict__ partial) {
    __shared__ __align__(16) short Ald[4096 * 8];      // 256 rows x 16 granules = 64 KB
    __shared__ __align__(16) short Bld[2 * 1280 * 8];  // 2 leaves x 80 rows x 16 g = 40 KB
    __shared__ float p_ld[256][4];                     // 4 KB

    const int tid = threadIdx.x;
    const int lane = tid & 63, wave = tid >> 6;        // 8 waves
    const int q = lane >> 4, r = lane & 15;
    const int wrow = wave * 32;                        // 8 x 32 = 256 rows
    const int lc = blockIdx.x & 63;   // 64 l-chunks of 4 leaves
    const int mt = blockIdx.x >> 6;   // 4 m-tiles of 256 rows

    if (tid < 256) {
        float4 pw = *(const float4*)(p + (size_t)(mt * 256 + tid) * L_ + lc * 4);
        p_ld[tid][0] = pw.x; p_ld[tid][1] = pw.y;
        p_ld[tid][2] = pw.z; p_ld[tid][3] = pw.w;
    }
    __syncthreads();  // p_ld visible

    // outacc init = bias term: sum_li p_ld[row][li] * lb[(lc*4+li)*80 + col]
    f32x4 outacc[2][5];
    #pragma unroll
    for (int nf = 0; nf < 5; ++nf) {
        float bv[4];
        #pragma unroll
        for (int li = 0; li < 4; ++li)
            bv[li] = lb[(size_t)(lc * 4 + li) * C_ + nf * 16 + r];
        #pragma unroll
        for (int mf = 0; mf < 2; ++mf)
            #pragma unroll
            for (int i = 0; i < 4; ++i) {
                int row = wrow + mf * 16 + q * 4 + i;
                outacc[mf][nf][i] = p_ld[row][0] * bv[0] + p_ld[row][1] * bv[1]
                                  + p_ld[row][2] * bv[2] + p_ld[row][3] * bv[3];
            }
    }

    const bf16x8* Av = (const bf16x8*)Ald;
    const f32x4 z4 = {0.f, 0.f, 0.f, 0.f};

    for (int kb = 0; kb < 4; ++kb) {      // 4 K=128 chunks, A staged once each
        for (int lp = 0; lp < 2; ++lp) {  // 2 leaf-PAIRS per kb -> 8 stages total
            __syncthreads();  // previous stage's readers done before overwrite
            if (lp == 0) {
                // stage A: 4096 granules (256 rows x 16), 8 per thread
                #pragma unroll
                for (int j = 0; j < 8; ++j) {
                    int ph = j * 512 + tid;
                    int rr = ph >> 4;
                    int g  = (ph & 15) ^ (rr & 15);
                    GLD(xb + ((size_t)(mt * 256 + rr) * D_ + kb * 128 + g * 8), Ald + ph * 8);
                }
            }
            // stage B: TWO leaves, 2 x 1280 granules (80 rows x 16), 5/thread
            #pragma unroll
            for (int l2 = 0; l2 < 2; ++l2) {
                const int l = lc * 4 + lp * 2 + l2;
                #pragma unroll
                for (int j = 0; j < 2; ++j) {
                    int ph = j * 512 + tid;
                    int cc = ph >> 4;
                    int g  = (ph & 15) ^ (cc & 15);
                    GLD(wb + ((size_t)(l * C_ + cc) * D_ + kb * 128 + g * 8),
                        Bld + (l2 * 1280 + ph) * 8);
                }
                if (tid < 256) {
                    int ph = 1024 + tid;
                    int cc = ph >> 4;
                    int g  = (ph & 15) ^ (cc & 15);
                    GLD(wb + ((size_t)(l * C_ + cc) * D_ + kb * 128 + g * 8),
                        Bld + (l2 * 1280 + ph) * 8);
                }
            }
            __syncthreads();  // drains vmcnt(0): tiles complete

            // process the two staged leaves SEQUENTIALLY (same dec regs)
            #pragma unroll
            for (int l2 = 0; l2 < 2; ++l2) {
                const bf16x8* Bv = (const bf16x8*)Bld + l2 * 1280;
                const int li = lp * 2 + l2;

                f32x4 dec[2][5];
                #pragma unroll
                for (int ks = 0; ks < 4; ++ks) {  // 4 K=32 slices -> 40 MFMA/leaf
                    const int g = ks * 4 + q;
                    bf16x8 af[2], bfr[5];
                    #pragma unroll
                    for (int mf = 0; mf < 2; ++mf) {
                        int rl = wrow + mf * 16 + r;
                        af[mf] = Av[rl * 16 + (g ^ (rl & 15))];
                    }
                    #pragma unroll
                    for (int nf = 0; nf < 5; ++nf) {
                        int cl = nf * 16 + r;
                        bfr[nf] = Bv[cl * 16 + (g ^ (cl & 15))];
                    }
                    #pragma unroll
                    for (int mf = 0; mf < 2; ++mf)
                        #pragma unroll
                        for (int nf = 0; nf < 5; ++nf)
                            dec[mf][nf] = __builtin_amdgcn_mfma_f32_16x16x32_bf16(
                                af[mf], bfr[nf], ks == 0 ? z4 : dec[mf][nf], 0, 0, 0);
                }

                // linear p-fold of this (kb,li) chunk; p read from LDS
                #pragma unroll
                for (int mf = 0; mf < 2; ++mf)
                    #pragma unroll
                    for (int i = 0; i < 4; ++i) {
                        float pf = p_ld[wrow + mf * 16 + q * 4 + i][li];
                        #pragma unroll
                        for (int nf = 0; nf < 5; ++nf)
                            outacc[mf][nf][i] += pf * dec[mf][nf][i];
                    }
            }
        }
    }

    // store partials: partial[lc][1024 rows][80 cols], this block owns 256 rows
    const size_t rbase = (size_t)lc * B_ + mt * 256;
    #pragma unroll
    for (int mf = 0; mf < 2; ++mf)
        #pragma unroll
        for (int nf = 0; nf < 5; ++nf)
            #pragma unroll
            for (int i = 0; i < 4; ++i) {
                int row = wrow + mf * 16 + q * 4 + i;
                int col = nf * 16 + r;
                partial[(rbase + row) * C_ + col] = outacc[mf][nf][i];
            }
}

// ---------------------------------------------------------------------------
// Kernel 5: reduce 64 lc partials -> out0 (1024x80).
// Grid 640 = 80 idx-chunks x 8 j-groups: each thread sums 8 slabs and
// atomicAdds (8-way contention only; out0 zeroed by leafprob).
// ---------------------------------------------------------------------------
__global__ __launch_bounds__(256) void reduce_kernel(const float* __restrict__ partial,
                                                     float* __restrict__ out0) {
    const int chunk = blockIdx.x >> 3;            // 0..79
    const int jg    = blockIdx.x & 7;             // 0..7
    const int idx   = chunk * 256 + threadIdx.x;  // float4 index < 20480
    const float4* p4 = (const float4*)partial;
    float4 s = {0.f, 0.f, 0.f, 0.f};
    #pragma unroll
    for (int j = 0; j < 8; ++j) {
        float4 v = p4[(size_t)(jg * 8 + j) * (B_ * C_ / 4) + idx];
        s.x += v.x; s.y += v.y; s.z += v.z; s.w += v.w;
    }
    float* o = out0 + (size_t)idx * 4;
    atomicAdd(o + 0, s.x);
    atomicAdd(o + 1, s.y);
    atomicAdd(o + 2, s.z);
    atomicAdd(o + 3, s.w);
}

// ---------------------------------------------------------------------------
extern "C" void kernel_launch(void* const* d_in, const int* in_sizes, int n_in,
                              void* d_out, int out_size, void* d_ws, size_t ws_size,
                              hipStream_t stream) {
    const float* x  = (const float*)d_in[0];  // 1024x512
    const float* ne = (const float*)d_in[1];  // 255x512
    const float* lW = (const float*)d_in[2];  // 20480x512
    const float* lb = (const float*)d_in[3];  // 20480
    // d_in[4] res_path: deterministic structure, traversed directly

    float* out0 = (float*)d_out;            // 1024x80
    float* out1 = out0 + (size_t)B_ * C_;   // 1024x255

    char* ws = (char*)d_ws;
    short* xb      = (short*)ws;                             // 1 MB
    short* neb     = (short*)(ws + (1u << 20));              // 256 KB
    float* p_ws    = (float*)(ws + (1u << 20) + (1u << 18)); // 1 MB
    short* wb      = (short*)(ws + (9u << 18));              // 20 MB @ 2.25 MB
    float* partial = (float*)(ws + (24u << 20));             // 21 MB (64x1024x80)

    convert_kernel<<<2304, 256, 0, stream>>>(lW, x, ne, wb, xb, neb);
    simgemm_kernel<<<64, 256, 0, stream>>>(xb, neb, out1);
    leafprob_kernel<<<B_, 256, 0, stream>>>(out1, p_ws, out0);
    gemm_kernel<<<256, 512, 0, stream>>>(xb, wb, p_ws, lb, partial);
    reduce_kernel<<<640, 256, 0, stream>>>(partial, out0);
}